// Round 8
// baseline (538.558 us; speedup 1.0000x reference)
//
#include <hip/hip_runtime.h>
#include <cstdint>
#include <cstddef>

typedef float floatx4 __attribute__((ext_vector_type(4)));
typedef short bf16x8 __attribute__((ext_vector_type(8)));

#define MFMA(a, b, c) __builtin_amdgcn_mfma_f32_16x16x32_bf16((a), (b), (c), 0, 0, 0)

__device__ __forceinline__ unsigned short f2bf(float f) {
  union { float f; unsigned int u; } v; v.f = f;
  unsigned int u = v.u;
  unsigned int r = (u + 0x7FFFu + ((u >> 16) & 1u)) >> 16;
  return (unsigned short)r;
}

__device__ __forceinline__ void gload_lds16(const unsigned short* g, unsigned short* s) {
  __builtin_amdgcn_global_load_lds(
      (const __attribute__((address_space(1))) unsigned int*)g,
      (__attribute__((address_space(3))) unsigned int*)s, 16, 0, 0);
}

__device__ __forceinline__ float gelu_f(float v) {
  float z = 0.7978845608028654f * (v + 0.044715f * v * v * v);
  float e = __expf(2.0f * z);
  float th = 1.0f - 2.0f / (e + 1.0f);
  return 0.5f * v * (1.0f + th);
}

// ------------------------------------------------------------------
// Fused prep: 6 weight transposes (ids 0..12287) + RMSNorm rows
// (ids 12288..20479).  Transpose: src [R,C] fp32 -> dst [C,R] bf16.
// ------------------------------------------------------------------
__global__ __launch_bounds__(256) void prep_all(
    const float* __restrict__ w_mlp_in, const float* __restrict__ wq,
    const float* __restrict__ wk, const float* __restrict__ wv,
    const float* __restrict__ w_mlp_out, const float* __restrict__ w_attn_out,
    const float* __restrict__ x, const float* __restrict__ pns,
    unsigned short* __restrict__ wcatT, unsigned short* __restrict__ wcat2T,
    unsigned short* __restrict__ xn) {
  __shared__ float tile[32][33];
  __shared__ float ws4[4];
  int id = blockIdx.x;
  if (id >= 12288) {
    // ---- RMSNorm row
    int row = id - 12288;
    const float4 v = ((const float4*)(x + (size_t)row * 1024))[threadIdx.x];
    float ss = v.x * v.x + v.y * v.y + v.z * v.z + v.w * v.w;
#pragma unroll
    for (int off = 1; off < 64; off <<= 1) ss += __shfl_xor(ss, off, 64);
    if ((threadIdx.x & 63) == 0) ws4[threadIdx.x >> 6] = ss;
    __syncthreads();
    float tot = ws4[0] + ws4[1] + ws4[2] + ws4[3];
    float rs = rsqrtf(tot * (1.0f / 1024.0f) + 1e-6f);
    const float4 sc = ((const float4*)pns)[threadIdx.x];
    uint2 o;
    o.x = (unsigned)f2bf(v.x * rs * sc.x) | ((unsigned)f2bf(v.y * rs * sc.y) << 16);
    o.y = (unsigned)f2bf(v.z * rs * sc.z) | ((unsigned)f2bf(v.w * rs * sc.w) << 16);
    ((uint2*)(xn + (size_t)row * 1024))[threadIdx.x] = o;
    return;
  }
  // ---- transpose tile
  const float* src; unsigned short* dst; int C, ldd, bx, by, q;
  if (id < 4096)       { src = w_mlp_in;   dst = wcatT;                        C = 4096; ldd = 1024; q = id;         bx = q & 127; by = q >> 7; }
  else if (id < 5120)  { src = wq;         dst = wcatT + (size_t)4096 * 1024;  C = 1024; ldd = 1024; q = id - 4096;  bx = q & 31;  by = q >> 5; }
  else if (id < 6144)  { src = wk;         dst = wcatT + (size_t)5120 * 1024;  C = 1024; ldd = 1024; q = id - 5120;  bx = q & 31;  by = q >> 5; }
  else if (id < 7168)  { src = wv;         dst = wcatT + (size_t)6144 * 1024;  C = 1024; ldd = 1024; q = id - 6144;  bx = q & 31;  by = q >> 5; }
  else if (id < 11264) { src = w_mlp_out;  dst = wcat2T;                       C = 1024; ldd = 5120; q = id - 7168;  bx = q & 31;  by = q >> 5; }
  else                 { src = w_attn_out; dst = wcat2T + 4096;                C = 1024; ldd = 5120; q = id - 11264; bx = q & 31;  by = q >> 5; }
  int tx = threadIdx.x & 31, ty = threadIdx.x >> 5;
#pragma unroll
  for (int i = 0; i < 4; i++) {
    int r = ty + i * 8;
    tile[r][tx] = src[(size_t)(by * 32 + r) * C + bx * 32 + tx];
  }
  __syncthreads();
#pragma unroll
  for (int i = 0; i < 4; i++) {
    int r = ty + i * 8;
    dst[(size_t)(bx * 32 + r) * ldd + by * 32 + tx] = f2bf(tile[tx][r]);
  }
}

// ------------------------------------------------------------------
// GEMM core: C[M,N] = A[M,K] * BT[N,K]^T (both bf16, K-major).
// 128x128 tile, BK=64 as 2 x 32-k sub-buffers, 4 waves x 64x64.
// Verbatim proven structure (160us @ N=7168 / MfmaUtil 33 / 0 bank
// conflicts); shared by the standalone kernel and the fused kernel.
// As/Bs: caller-provided LDS, 2 buffers x 4096 shorts each.
//
// nt-stores on all epilogue writes (proven -37us: streaming writes
// were evicting the per-XCD B-panel from L2).  f2bf everywhere
// (cvt_pk rounding tripled absmax).
//
// MODE 7: out[row*1024+col] = v + b1[col] + b2[col] + resid
// MODE 8: MLP only (N=4096): gelu -> cat[row*5120+col]
// MODE 9: QKV only (N=3072): seg=n0>>10; q*0.125/k -> [B,H,S,HD],
//         v -> [B,H,HD,S]
// ------------------------------------------------------------------
template <int MODE>
__device__ __forceinline__ void gemm_core(
    int xcd, int j,
    const unsigned short* __restrict__ A, const unsigned short* __restrict__ BT,
    int K, void* __restrict__ outp,
    const float* __restrict__ bias1, const float* __restrict__ bias2,
    const float* __restrict__ resid,
    int msplit, int tm, int tn,
    unsigned short* __restrict__ q_out, unsigned short* __restrict__ k_out,
    unsigned short* __restrict__ v_out,
    unsigned short* As, unsigned short* Bs) {
  int mh = xcd % msplit, nq = xcd / msplit;
  int by = mh * tm + j / tn;
  int bx = nq * tn + j % tn;
  int m0 = by * 128, n0 = bx * 128;

  int t = threadIdx.x, lane = t & 63, wave = t >> 6;
  int l15 = lane & 15, quad = lane >> 4;
  int wm = (wave & 1) * 64, wn = (wave >> 1) * 64;

  floatx4 acc[4][4] = {};

  int lr = lane >> 2;
  int lg = (lane & 3) ^ ((lane >> 3) & 3);
  int ch0 = wave * 2, ch1 = wave * 2 + 1;
  const unsigned short* gA0 = A + (size_t)(m0 + ch0 * 16 + lr) * K + lg * 8;
  const unsigned short* gA1 = A + (size_t)(m0 + ch1 * 16 + lr) * K + lg * 8;
  const unsigned short* gB0 = BT + (size_t)(n0 + ch0 * 16 + lr) * K + lg * 8;
  const unsigned short* gB1 = BT + (size_t)(n0 + ch1 * 16 + lr) * K + lg * 8;
  unsigned short* sA0[2] = {As + ch0 * 512 + lane * 8, As + 4096 + ch0 * 512 + lane * 8};
  unsigned short* sA1[2] = {As + ch1 * 512 + lane * 8, As + 4096 + ch1 * 512 + lane * 8};
  unsigned short* sB0[2] = {Bs + ch0 * 512 + lane * 8, Bs + 4096 + ch0 * 512 + lane * 8};
  unsigned short* sB1[2] = {Bs + ch1 * 512 + lane * 8, Bs + 4096 + ch1 * 512 + lane * 8};

  int fo = (4 * l15 + (quad ^ ((l15 >> 1) & 3))) * 8;
  int ca = (wm >> 4);
  int cb = (wn >> 4);

  for (int kt = 0; kt < K; kt += 64) {
    __syncthreads();
#pragma unroll
    for (int kk = 0; kk < 2; kk++) {
      int kg = kt + kk * 32;
      gload_lds16(gA0 + kg, sA0[kk]);
      gload_lds16(gA1 + kg, sA1[kk]);
      gload_lds16(gB0 + kg, sB0[kk]);
      gload_lds16(gB1 + kg, sB1[kk]);
    }
    __syncthreads();
#pragma unroll
    for (int kk = 0; kk < 2; kk++) {
      bf16x8 a[4], b[4];
#pragma unroll
      for (int im = 0; im < 4; im++)
        a[im] = *(const bf16x8*)&As[kk * 4096 + (ca + im) * 512 + fo];
#pragma unroll
      for (int in_ = 0; in_ < 4; in_++)
        b[in_] = *(const bf16x8*)&Bs[kk * 4096 + (cb + in_) * 512 + fo];
#pragma unroll
      for (int im = 0; im < 4; im++)
#pragma unroll
        for (int in_ = 0; in_ < 4; in_++)
          acc[im][in_] = MFMA(a[im], b[in_], acc[im][in_]);
    }
  }

#pragma unroll
  for (int im = 0; im < 4; im++) {
#pragma unroll
    for (int in_ = 0; in_ < 4; in_++) {
      int row0 = m0 + wm + im * 16 + quad * 4;
      int col = n0 + wn + in_ * 16 + l15;
      if constexpr (MODE == 8) {
#pragma unroll
        for (int r = 0; r < 4; r++) {
          __builtin_nontemporal_store(f2bf(gelu_f(acc[im][in_][r])),
              &((unsigned short*)outp)[(size_t)(row0 + r) * 5120 + col]);
        }
      } else if constexpr (MODE == 9) {
        int seg = n0 >> 10;                   // 0=q 1=k 2=v (tile-uniform)
        int cs = col - (seg << 10);
        int h = cs >> 6, hd = cs & 63;
        int b_ = row0 >> 11, s0 = row0 & 2047;
        if (seg == 2) {
          unsigned long long o =
              (unsigned long long)((unsigned)f2bf(acc[im][in_][0]) |
                                   ((unsigned)f2bf(acc[im][in_][1]) << 16)) |
              ((unsigned long long)((unsigned)f2bf(acc[im][in_][2]) |
                                    ((unsigned)f2bf(acc[im][in_][3]) << 16)) << 32);
          __builtin_nontemporal_store(o,
              (unsigned long long*)&v_out[(((size_t)(b_ * 16 + h)) * 64 + hd) * 2048 + s0]);
        } else {
          float sc = (seg == 0) ? 0.125f : 1.0f;
          unsigned short* dst = (seg == 0) ? q_out : k_out;
#pragma unroll
          for (int r = 0; r < 4; r++) {
            __builtin_nontemporal_store(f2bf(acc[im][in_][r] * sc),
                &dst[(((size_t)(b_ * 16 + h)) * 2048 + s0 + r) * 64 + hd]);
          }
        }
      } else {  // MODE 7
        float bsum = bias1[col] + bias2[col];
#pragma unroll
        for (int r = 0; r < 4; r++) {
          size_t idx = (size_t)(row0 + r) * 1024 + col;
          float res = __builtin_nontemporal_load(&resid[idx]);
          __builtin_nontemporal_store(acc[im][in_][r] + bsum + res, &((float*)outp)[idx]);
        }
      }
    }
  }
}

template <int MODE>
__global__ __launch_bounds__(256, 2) void gemm_bt(
    const unsigned short* __restrict__ A, const unsigned short* __restrict__ BT,
    int K, void* __restrict__ outp,
    const float* __restrict__ bias1, const float* __restrict__ bias2,
    const float* __restrict__ resid,
    int msplit, int tm, int tn,
    unsigned short* __restrict__ q_out, unsigned short* __restrict__ k_out,
    unsigned short* __restrict__ v_out) {
  __shared__ unsigned short As[2 * 128 * 32];
  __shared__ unsigned short Bs[2 * 128 * 32];
  int id = blockIdx.x + gridDim.x * blockIdx.y;
  gemm_core<MODE>(id & 7, id >> 3, A, BT, K, outp, bias1, bias2, resid,
                  msplit, tm, tn, q_out, k_out, v_out, As, Bs);
}

// ------------------------------------------------------------------
// Flash attention body -- R0 VERBATIM inner code (the only flash
// config with a known-good measurement; R3/R4/R6 restructures all
// regressed).  q pre-scaled by 0.125.  q,k [B,H,S,HD]; v [B,H,HD,S].
// av -> cat cols 4096..5120.  4 waves x 32 q rows; kv tile 64.
// LDS carved from smem: Ks 64*72, Vs 64*72, Ps 4*32*68 shorts.
// ------------------------------------------------------------------
__device__ __forceinline__ void flash_body(
    int xcd, int j,
    const unsigned short* __restrict__ q_buf, const unsigned short* __restrict__ k_buf,
    const unsigned short* __restrict__ v_buf, unsigned short* __restrict__ cat,
    unsigned short* smem) {
  constexpr int S = 2048, HD = 64;
  constexpr int LK = 72, LV = 72, LP = 68;
  unsigned short* Ks = smem;                 // 64*72 = 4608
  unsigned short* Vs = smem + 4608;          // 64*72 = 4608
  unsigned short* Psb = smem + 9216;         // 4*32*68 = 8704  (total 17920)

  int bh = xcd * 8 + (j >> 4);
  int qbk = j & 15;

  int t = threadIdx.x, lane = t & 63, wave = t >> 6;
  int l15 = lane & 15, quad = lane >> 4;
  unsigned short* Ps = Psb + wave * (32 * LP);

  const unsigned short* qp = q_buf + (size_t)bh * S * HD;
  const unsigned short* kp = k_buf + (size_t)bh * S * HD;
  const unsigned short* vp = v_buf + (size_t)bh * HD * S;

  int q0 = qbk * 128 + wave * 32;
  bf16x8 aQ[2][2];
#pragma unroll
  for (int qf = 0; qf < 2; qf++) {
    aQ[qf][0] = *(const bf16x8*)&qp[(size_t)(q0 + qf * 16 + l15) * HD + quad * 8];
    aQ[qf][1] = *(const bf16x8*)&qp[(size_t)(q0 + qf * 16 + l15) * HD + 32 + quad * 8];
  }

  floatx4 acc_o[2][4] = {};
  float lrow[2][4] = {};

  int kr = t >> 3, kc = (t & 7) * 8;

  uint4 rK0 = *(const uint4*)&kp[(size_t)kr * HD + kc];
  uint4 rK1 = *(const uint4*)&kp[(size_t)(kr + 32) * HD + kc];
  uint4 rV0 = *(const uint4*)&vp[(size_t)kr * S + kc];
  uint4 rV1 = *(const uint4*)&vp[(size_t)(kr + 32) * S + kc];

  for (int kv = 0; kv < S; kv += 64) {
    __syncthreads();
    *(uint4*)&Ks[kr * LK + kc] = rK0;
    *(uint4*)&Ks[(kr + 32) * LK + kc] = rK1;
    *(uint4*)&Vs[kr * LV + kc] = rV0;
    *(uint4*)&Vs[(kr + 32) * LV + kc] = rV1;
    __syncthreads();
    if (kv + 64 < S) {
      rK0 = *(const uint4*)&kp[(size_t)(kv + 64 + kr) * HD + kc];
      rK1 = *(const uint4*)&kp[(size_t)(kv + 64 + kr + 32) * HD + kc];
      rV0 = *(const uint4*)&vp[(size_t)kr * S + kv + 64 + kc];
      rV1 = *(const uint4*)&vp[(size_t)(kr + 32) * S + kv + 64 + kc];
    }

    floatx4 z[2][4];
#pragma unroll
    for (int cg = 0; cg < 4; cg++) {
      bf16x8 bk0 = *(const bf16x8*)&Ks[(cg * 16 + l15) * LK + quad * 8];
      bf16x8 bk1 = *(const bf16x8*)&Ks[(cg * 16 + l15) * LK + 32 + quad * 8];
#pragma unroll
      for (int qf = 0; qf < 2; qf++) {
        floatx4 acc = {};
        acc = MFMA(aQ[qf][0], bk0, acc);
        acc = MFMA(aQ[qf][1], bk1, acc);
        z[qf][cg] = acc;
      }
    }
#pragma unroll
    for (int qf = 0; qf < 2; qf++)
#pragma unroll
      for (int cg = 0; cg < 4; cg++)
#pragma unroll
        for (int r = 0; r < 4; r++) {
          float e = __expf(z[qf][cg][r]);
          lrow[qf][r] += e;
          Ps[(qf * 16 + quad * 4 + r) * LP + cg * 16 + l15] = f2bf(e);
        }
    asm volatile("s_waitcnt lgkmcnt(0)" ::: "memory");
#pragma unroll
    for (int c = 0; c < 2; c++) {
      bf16x8 aP[2];
#pragma unroll
      for (int qf = 0; qf < 2; qf++) {
        const unsigned short* pp = &Ps[(qf * 16 + l15) * LP + c * 32 + quad * 8];
        ((uint2*)&aP[qf])[0] = *(const uint2*)pp;
        ((uint2*)&aP[qf])[1] = *(const uint2*)(pp + 4);
      }
#pragma unroll
      for (int n = 0; n < 4; n++) {
        bf16x8 bv = *(const bf16x8*)&Vs[(n * 16 + l15) * LV + c * 32 + quad * 8];
        acc_o[0][n] = MFMA(aP[0], bv, acc_o[0][n]);
        acc_o[1][n] = MFMA(aP[1], bv, acc_o[1][n]);
      }
    }
  }

#pragma unroll
  for (int qf = 0; qf < 2; qf++)
#pragma unroll
    for (int r = 0; r < 4; r++) {
      float s = lrow[qf][r];
#pragma unroll
      for (int off = 1; off < 16; off <<= 1) s += __shfl_xor(s, off, 16);
      lrow[qf][r] = s;
    }

  int b_ = bh >> 4, h = bh & 15;
#pragma unroll
  for (int qf = 0; qf < 2; qf++)
#pragma unroll
    for (int r = 0; r < 4; r++) {
      float inv = 1.0f / lrow[qf][r];
      int srow = q0 + qf * 16 + quad * 4 + r;
      size_t base = ((size_t)(b_ * 2048 + srow)) * 5120 + 4096 + h * 64;
#pragma unroll
      for (int n = 0; n < 4; n++)
        cat[base + n * 16 + l15] = f2bf(acc_o[qf][n][r] * inv);
    }
}

// ------------------------------------------------------------------
// Fused launch: flash attention (1024 blocks) + MLP-input GEMM
// (2048 blocks, [8192,1024]x[4096,1024]^T -> gelu -> cat).  The two
// are independent (flash reads qb/kb/vb from the earlier QKV GEMM;
// MLP writes cat cols 0..4096, flash writes 4096..5120).  Interleaved
// per-XCD (r%3==2 -> flash) so each CU co-hosts both kinds: the
// MFMA-heavy GEMM fills flash's barrier/latency stalls (m114: MFMA
// and VALU waves on one CU overlap fully).  LDS union 35840 B.
// ------------------------------------------------------------------
__global__ __launch_bounds__(256, 2) void fused_mlp_attn(
    const unsigned short* __restrict__ xn, const unsigned short* __restrict__ wcatT,
    unsigned short* __restrict__ cat,
    const unsigned short* __restrict__ qb, const unsigned short* __restrict__ kb,
    const unsigned short* __restrict__ vb) {
  __shared__ __align__(16) unsigned short smem[17920];
  int phys = blockIdx.x;
  int xcd = phys & 7, r = phys >> 3;        // r in [0,384) per XCD
  if (r % 3 == 2) {
    flash_body(xcd, r / 3, qb, kb, vb, cat, smem);
  } else {
    int g = (r / 3) * 2 + (r % 3);          // 0..255 per XCD
    gemm_core<8>(xcd, g, xn, wcatT, 1024, cat, nullptr, nullptr, nullptr,
                 2, 32, 8, nullptr, nullptr, nullptr, smem, smem + 8192);
  }
}

// ------------------------------------------------------------------
extern "C" void kernel_launch(void* const* d_in, const int* in_sizes, int n_in,
                              void* d_out, int out_size, void* d_ws, size_t ws_size,
                              hipStream_t stream) {
  (void)in_sizes; (void)n_in; (void)out_size; (void)ws_size;
  const float* x          = (const float*)d_in[0];
  const float* pns        = (const float*)d_in[1];
  const float* w_mlp_in   = (const float*)d_in[2];
  const float* wq         = (const float*)d_in[3];
  const float* wk         = (const float*)d_in[4];
  const float* wv         = (const float*)d_in[5];
  const float* w_mlp_out  = (const float*)d_in[6];
  const float* b_mlp_out  = (const float*)d_in[7];
  const float* w_attn_out = (const float*)d_in[8];
  const float* b_attn_out = (const float*)d_in[9];
  float* out = (float*)d_out;

  char* ws = (char*)d_ws;
  size_t off = 0;
  auto alloc = [&](size_t bytes) {
    void* p = ws + off;
    off += (bytes + 255) & ~(size_t)255;
    return p;
  };
  const size_t M = 8192;
  unsigned short* xn     = (unsigned short*)alloc(M * 1024 * 2);
  unsigned short* wcatT  = (unsigned short*)alloc((size_t)7168 * 1024 * 2);  // [mlp_in|q|k|v][N,K]
  unsigned short* wcat2T = (unsigned short*)alloc((size_t)1024 * 5120 * 2);  // [N=1024, K=5120]
  unsigned short* cat    = (unsigned short*)alloc(M * 5120 * 2);             // [h | av]
  unsigned short* qb     = (unsigned short*)alloc(M * 1024 * 2);
  unsigned short* kb     = (unsigned short*)alloc(M * 1024 * 2);
  unsigned short* vb     = (unsigned short*)alloc(M * 1024 * 2);

  // fused transposes + rmsnorm (independent; feed the GEMMs)
  prep_all<<<dim3(20480), 256, 0, stream>>>(
      w_mlp_in, wq, wk, wv, w_mlp_out, w_attn_out, x, pns, wcatT, wcat2T, xn);

  // QKV GEMM: [8192,1024] x [3072,1024]^T; 24 N-tiles -> tn=6,
  // grid 1536 blocks; scatters q/k/v.
  gemm_bt<9><<<dim3(1536), 256, 0, stream>>>(
      xn, wcatT + (size_t)4096 * 1024, 1024, nullptr, nullptr, nullptr, nullptr,
      2, 32, 6, qb, kb, vb);

  // fused: flash attention (1024 blocks) + MLP GEMM (2048 blocks,
  // 32 N-tiles -> tn=8), interleaved per-XCD.
  fused_mlp_attn<<<dim3(3072), 256, 0, stream>>>(xn, wcatT, cat, qb, kb, vb);

  // output GEMM: [8192,5120] x [1024,5120]^T; grid 8x64 = 512 blocks
  gemm_bt<7><<<dim3(8, 64), 256, 0, stream>>>(
      cat, wcat2T, 5120, out, b_mlp_out, b_attn_out, x, 2, 32, 2, nullptr, nullptr, nullptr);
}

// Round 9
// 534.389 us; speedup vs baseline: 1.0078x; 1.0078x over previous
//
#include <hip/hip_runtime.h>
#include <cstdint>
#include <cstddef>

typedef float floatx4 __attribute__((ext_vector_type(4)));
typedef short bf16x8 __attribute__((ext_vector_type(8)));

#define MFMA(a, b, c) __builtin_amdgcn_mfma_f32_16x16x32_bf16((a), (b), (c), 0, 0, 0)

__device__ __forceinline__ unsigned short f2bf(float f) {
  union { float f; unsigned int u; } v; v.f = f;
  unsigned int u = v.u;
  unsigned int r = (u + 0x7FFFu + ((u >> 16) & 1u)) >> 16;
  return (unsigned short)r;
}

__device__ __forceinline__ void gload_lds16(const unsigned short* g, unsigned short* s) {
  __builtin_amdgcn_global_load_lds(
      (const __attribute__((address_space(1))) unsigned int*)g,
      (__attribute__((address_space(3))) unsigned int*)s, 16, 0, 0);
}

__device__ __forceinline__ float gelu_f(float v) {
  float z = 0.7978845608028654f * (v + 0.044715f * v * v * v);
  float e = __expf(2.0f * z);
  float th = 1.0f - 2.0f / (e + 1.0f);
  return 0.5f * v * (1.0f + th);
}

// ------------------------------------------------------------------
// Fused prep: 6 weight transposes (ids 0..12287) + RMSNorm rows
// (ids 12288..20479).  Transpose: src [R,C] fp32 -> dst [C,R] bf16.
// ------------------------------------------------------------------
__global__ __launch_bounds__(256) void prep_all(
    const float* __restrict__ w_mlp_in, const float* __restrict__ wq,
    const float* __restrict__ wk, const float* __restrict__ wv,
    const float* __restrict__ w_mlp_out, const float* __restrict__ w_attn_out,
    const float* __restrict__ x, const float* __restrict__ pns,
    unsigned short* __restrict__ wcatT, unsigned short* __restrict__ wcat2T,
    unsigned short* __restrict__ xn) {
  __shared__ float tile[32][33];
  __shared__ float ws4[4];
  int id = blockIdx.x;
  if (id >= 12288) {
    // ---- RMSNorm row
    int row = id - 12288;
    const float4 v = ((const float4*)(x + (size_t)row * 1024))[threadIdx.x];
    float ss = v.x * v.x + v.y * v.y + v.z * v.z + v.w * v.w;
#pragma unroll
    for (int off = 1; off < 64; off <<= 1) ss += __shfl_xor(ss, off, 64);
    if ((threadIdx.x & 63) == 0) ws4[threadIdx.x >> 6] = ss;
    __syncthreads();
    float tot = ws4[0] + ws4[1] + ws4[2] + ws4[3];
    float rs = rsqrtf(tot * (1.0f / 1024.0f) + 1e-6f);
    const float4 sc = ((const float4*)pns)[threadIdx.x];
    uint2 o;
    o.x = (unsigned)f2bf(v.x * rs * sc.x) | ((unsigned)f2bf(v.y * rs * sc.y) << 16);
    o.y = (unsigned)f2bf(v.z * rs * sc.z) | ((unsigned)f2bf(v.w * rs * sc.w) << 16);
    ((uint2*)(xn + (size_t)row * 1024))[threadIdx.x] = o;
    return;
  }
  // ---- transpose tile
  const float* src; unsigned short* dst; int C, ldd, bx, by, q;
  if (id < 4096)       { src = w_mlp_in;   dst = wcatT;                        C = 4096; ldd = 1024; q = id;         bx = q & 127; by = q >> 7; }
  else if (id < 5120)  { src = wq;         dst = wcatT + (size_t)4096 * 1024;  C = 1024; ldd = 1024; q = id - 4096;  bx = q & 31;  by = q >> 5; }
  else if (id < 6144)  { src = wk;         dst = wcatT + (size_t)5120 * 1024;  C = 1024; ldd = 1024; q = id - 5120;  bx = q & 31;  by = q >> 5; }
  else if (id < 7168)  { src = wv;         dst = wcatT + (size_t)6144 * 1024;  C = 1024; ldd = 1024; q = id - 6144;  bx = q & 31;  by = q >> 5; }
  else if (id < 11264) { src = w_mlp_out;  dst = wcat2T;                       C = 1024; ldd = 5120; q = id - 7168;  bx = q & 31;  by = q >> 5; }
  else                 { src = w_attn_out; dst = wcat2T + 4096;                C = 1024; ldd = 5120; q = id - 11264; bx = q & 31;  by = q >> 5; }
  int tx = threadIdx.x & 31, ty = threadIdx.x >> 5;
#pragma unroll
  for (int i = 0; i < 4; i++) {
    int r = ty + i * 8;
    tile[r][tx] = src[(size_t)(by * 32 + r) * C + bx * 32 + tx];
  }
  __syncthreads();
#pragma unroll
  for (int i = 0; i < 4; i++) {
    int r = ty + i * 8;
    dst[(size_t)(bx * 32 + r) * ldd + by * 32 + tx] = f2bf(tile[tx][r]);
  }
}

// ------------------------------------------------------------------
// GEMM: C[M,N] = A[M,K] * BT[N,K]^T (both bf16, K-major).  128x128
// tile, BK=64 as 2 x 32-k sub-buffers, 4 waves x 64x64.
// R7 version, measured 160 us MODE6 / MfmaUtil 33.7 / FETCH 127 MB.
//
// nt-stores on all epilogue writes: streaming writes were evicting
// the per-XCD B-panel from L2 (-37us).  f2bf everywhere (cvt_pk
// rounding tripled absmax).
//
// HYBRID SWIZZLE (0 bank conflicts measured): staging lane L ->
// (row L>>2, granule (L&3)^((L>>3)&3)); frag read
// fo=(4*l15+(quad^((l15>>1)&3)))*8.
// ------------------------------------------------------------------
template <int MODE>
__global__ __launch_bounds__(256, 2) void gemm_bt(
    const unsigned short* __restrict__ A, const unsigned short* __restrict__ BT,
    int K, void* __restrict__ outp,
    const float* __restrict__ bias1, const float* __restrict__ bias2,
    const float* __restrict__ resid,
    int msplit, int tm, int tn,
    unsigned short* __restrict__ q_out, unsigned short* __restrict__ k_out,
    unsigned short* __restrict__ v_out) {
  __shared__ unsigned short As[2][128 * 32];
  __shared__ unsigned short Bs[2][128 * 32];

  int id = blockIdx.x + gridDim.x * blockIdx.y;
  int xcd = id & 7, j = id >> 3;
  int mh = xcd % msplit, nq = xcd / msplit;
  int by = mh * tm + j / tn;
  int bx = nq * tn + j % tn;
  int m0 = by * 128, n0 = bx * 128;

  int t = threadIdx.x, lane = t & 63, wave = t >> 6;
  int l15 = lane & 15, quad = lane >> 4;
  int wm = (wave & 1) * 64, wn = (wave >> 1) * 64;

  floatx4 acc[4][4] = {};

  int lr = lane >> 2;
  int lg = (lane & 3) ^ ((lane >> 3) & 3);
  int ch0 = wave * 2, ch1 = wave * 2 + 1;
  const unsigned short* gA0 = A + (size_t)(m0 + ch0 * 16 + lr) * K + lg * 8;
  const unsigned short* gA1 = A + (size_t)(m0 + ch1 * 16 + lr) * K + lg * 8;
  const unsigned short* gB0 = BT + (size_t)(n0 + ch0 * 16 + lr) * K + lg * 8;
  const unsigned short* gB1 = BT + (size_t)(n0 + ch1 * 16 + lr) * K + lg * 8;
  unsigned short* sA0[2] = {&As[0][ch0 * 512 + lane * 8], &As[1][ch0 * 512 + lane * 8]};
  unsigned short* sA1[2] = {&As[0][ch1 * 512 + lane * 8], &As[1][ch1 * 512 + lane * 8]};
  unsigned short* sB0[2] = {&Bs[0][ch0 * 512 + lane * 8], &Bs[1][ch0 * 512 + lane * 8]};
  unsigned short* sB1[2] = {&Bs[0][ch1 * 512 + lane * 8], &Bs[1][ch1 * 512 + lane * 8]};

  int fo = (4 * l15 + (quad ^ ((l15 >> 1) & 3))) * 8;
  int ca = (wm >> 4);
  int cb = (wn >> 4);

  for (int kt = 0; kt < K; kt += 64) {
    __syncthreads();
#pragma unroll
    for (int kk = 0; kk < 2; kk++) {
      int kg = kt + kk * 32;
      gload_lds16(gA0 + kg, sA0[kk]);
      gload_lds16(gA1 + kg, sA1[kk]);
      gload_lds16(gB0 + kg, sB0[kk]);
      gload_lds16(gB1 + kg, sB1[kk]);
    }
    __syncthreads();
#pragma unroll
    for (int kk = 0; kk < 2; kk++) {
      bf16x8 a[4], b[4];
#pragma unroll
      for (int im = 0; im < 4; im++)
        a[im] = *(const bf16x8*)&As[kk][(ca + im) * 512 + fo];
#pragma unroll
      for (int in_ = 0; in_ < 4; in_++)
        b[in_] = *(const bf16x8*)&Bs[kk][(cb + in_) * 512 + fo];
#pragma unroll
      for (int im = 0; im < 4; im++)
#pragma unroll
        for (int in_ = 0; in_ < 4; in_++)
          acc[im][in_] = MFMA(a[im], b[in_], acc[im][in_]);
    }
  }

#pragma unroll
  for (int im = 0; im < 4; im++) {
#pragma unroll
    for (int in_ = 0; in_ < 4; in_++) {
      int row0 = m0 + wm + im * 16 + quad * 4;
      int col = n0 + wn + in_ * 16 + l15;
      if constexpr (MODE == 6) {
        if (n0 < 4096) {
#pragma unroll
          for (int r = 0; r < 4; r++) {
            __builtin_nontemporal_store(f2bf(gelu_f(acc[im][in_][r])),
                &((unsigned short*)outp)[(size_t)(row0 + r) * 5120 + col]);
          }
        } else {
          int seg = (n0 - 4096) >> 10;          // 0=q 1=k 2=v (tile-uniform)
          int cs = col - 4096 - (seg << 10);
          int h = cs >> 6, hd = cs & 63;
          int b_ = row0 >> 11, s0 = row0 & 2047;
          if (seg == 2) {
            // s-consecutive: pack 4 bf16 -> one 64-bit store
            unsigned long long o =
                (unsigned long long)((unsigned)f2bf(acc[im][in_][0]) |
                                     ((unsigned)f2bf(acc[im][in_][1]) << 16)) |
                ((unsigned long long)((unsigned)f2bf(acc[im][in_][2]) |
                                      ((unsigned)f2bf(acc[im][in_][3]) << 16)) << 32);
            __builtin_nontemporal_store(o,
                (unsigned long long*)&v_out[(((size_t)(b_ * 16 + h)) * 64 + hd) * 2048 + s0]);
          } else {
            float sc = (seg == 0) ? 0.125f : 1.0f;
            unsigned short* dst = (seg == 0) ? q_out : k_out;
#pragma unroll
            for (int r = 0; r < 4; r++) {
              __builtin_nontemporal_store(f2bf(acc[im][in_][r] * sc),
                  &dst[(((size_t)(b_ * 16 + h)) * 2048 + s0 + r) * 64 + hd]);
            }
          }
        }
      } else {
        float bsum = bias1[col] + bias2[col];
#pragma unroll
        for (int r = 0; r < 4; r++) {
          size_t idx = (size_t)(row0 + r) * 1024 + col;
          float res = __builtin_nontemporal_load(&resid[idx]);
          __builtin_nontemporal_store(acc[im][in_][r] + bsum + res, &((float*)outp)[idx]);
        }
      }
    }
  }
}

// ------------------------------------------------------------------
// Flash attention, no-max additive variant.  R0 structure (the only
// proven one; every schedule restructure regressed), with ONE change:
//
// R9: Ks/Vs XOR-SWIZZLED, rows of 64 shorts (no pad).
//   addr(row, g) = row*64 + ((g ^ (row&7))*8),  g = 16B granule 0..7.
// Old layout (stride 72 shorts = 144 B) gave b128 frag reads a bank
// start of 4*(l15+quad) mod 32 -> 8 distinct starts over 64 lanes =
// 8-way conflict (m136: 2.94x LDS-pipe inflation) on all 16 K/V
// reads per iter; measured 8.4M conflict-cycles/dispatch in R8's
// fused launch (gemm core is measured 0, so all flash).
// After swizzle: reads of row cg*16+l15 have row&7 = l15&7 -> 8
// consecutive lanes hit 8 distinct granules = 32 banks exactly once;
// writes (lane t -> row t>>3, granule t&7) likewise phase-perfect.
// XOR is a permutation per row -> bijective.  Ps untouched.
// ------------------------------------------------------------------
__device__ __forceinline__ int swz(int row, int g) {
  return row * 64 + ((g ^ (row & 7)) * 8);
}

__global__ __launch_bounds__(256, 2) void flash_attn(
    const unsigned short* __restrict__ q_buf, const unsigned short* __restrict__ k_buf,
    const unsigned short* __restrict__ v_buf, unsigned short* __restrict__ cat) {
  constexpr int S = 2048, HD = 64;
  constexpr int LP = 68;
  __shared__ unsigned short Ks[64 * 64];
  __shared__ unsigned short Vs[64 * 64];
  __shared__ unsigned short Ps[4][32 * LP];

  int id = blockIdx.x + gridDim.x * blockIdx.y;   // grid (16, 64)
  int xcd = id & 7, j = id >> 3;                  // j in [0,128)
  int bh = xcd * 8 + (j >> 4);
  int qbk = j & 15;

  int t = threadIdx.x, lane = t & 63, wave = t >> 6;
  int l15 = lane & 15, quad = lane >> 4;

  const unsigned short* qp = q_buf + (size_t)bh * S * HD;
  const unsigned short* kp = k_buf + (size_t)bh * S * HD;
  const unsigned short* vp = v_buf + (size_t)bh * HD * S;

  int q0 = qbk * 128 + wave * 32;
  bf16x8 aQ[2][2];
#pragma unroll
  for (int qf = 0; qf < 2; qf++) {
    aQ[qf][0] = *(const bf16x8*)&qp[(size_t)(q0 + qf * 16 + l15) * HD + quad * 8];
    aQ[qf][1] = *(const bf16x8*)&qp[(size_t)(q0 + qf * 16 + l15) * HD + 32 + quad * 8];
  }

  floatx4 acc_o[2][4] = {};
  float lrow[2][4] = {};

  int kr = t >> 3, kg = t & 7;   // staging: row t>>3, 16B granule t&7

  uint4 rK0 = *(const uint4*)&kp[(size_t)kr * HD + kg * 8];
  uint4 rK1 = *(const uint4*)&kp[(size_t)(kr + 32) * HD + kg * 8];
  uint4 rV0 = *(const uint4*)&vp[(size_t)kr * S + kg * 8];
  uint4 rV1 = *(const uint4*)&vp[(size_t)(kr + 32) * S + kg * 8];

  for (int kv = 0; kv < S; kv += 64) {
    __syncthreads();
    *(uint4*)&Ks[swz(kr, kg)] = rK0;
    *(uint4*)&Ks[swz(kr + 32, kg)] = rK1;
    *(uint4*)&Vs[swz(kr, kg)] = rV0;
    *(uint4*)&Vs[swz(kr + 32, kg)] = rV1;
    __syncthreads();
    if (kv + 64 < S) {
      rK0 = *(const uint4*)&kp[(size_t)(kv + 64 + kr) * HD + kg * 8];
      rK1 = *(const uint4*)&kp[(size_t)(kv + 64 + kr + 32) * HD + kg * 8];
      rV0 = *(const uint4*)&vp[(size_t)kr * S + kv + 64 + kg * 8];
      rV1 = *(const uint4*)&vp[(size_t)(kr + 32) * S + kv + 64 + kg * 8];
    }

    floatx4 z[2][4];
#pragma unroll
    for (int cg = 0; cg < 4; cg++) {
      bf16x8 bk0 = *(const bf16x8*)&Ks[swz(cg * 16 + l15, quad)];
      bf16x8 bk1 = *(const bf16x8*)&Ks[swz(cg * 16 + l15, quad + 4)];
#pragma unroll
      for (int qf = 0; qf < 2; qf++) {
        floatx4 acc = {};
        acc = MFMA(aQ[qf][0], bk0, acc);
        acc = MFMA(aQ[qf][1], bk1, acc);
        z[qf][cg] = acc;
      }
    }
#pragma unroll
    for (int qf = 0; qf < 2; qf++)
#pragma unroll
      for (int cg = 0; cg < 4; cg++)
#pragma unroll
        for (int r = 0; r < 4; r++) {
          float e = __expf(z[qf][cg][r]);
          lrow[qf][r] += e;
          Ps[wave][(qf * 16 + quad * 4 + r) * LP + cg * 16 + l15] = f2bf(e);
        }
    asm volatile("s_waitcnt lgkmcnt(0)" ::: "memory");
#pragma unroll
    for (int c = 0; c < 2; c++) {
      bf16x8 aP[2];
#pragma unroll
      for (int qf = 0; qf < 2; qf++) {
        const unsigned short* pp = &Ps[wave][(qf * 16 + l15) * LP + c * 32 + quad * 8];
        ((uint2*)&aP[qf])[0] = *(const uint2*)pp;
        ((uint2*)&aP[qf])[1] = *(const uint2*)(pp + 4);
      }
#pragma unroll
      for (int n = 0; n < 4; n++) {
        bf16x8 bv = *(const bf16x8*)&Vs[swz(n * 16 + l15, c * 4 + quad)];
        acc_o[0][n] = MFMA(aP[0], bv, acc_o[0][n]);
        acc_o[1][n] = MFMA(aP[1], bv, acc_o[1][n]);
      }
    }
  }

#pragma unroll
  for (int qf = 0; qf < 2; qf++)
#pragma unroll
    for (int r = 0; r < 4; r++) {
      float s = lrow[qf][r];
#pragma unroll
      for (int off = 1; off < 16; off <<= 1) s += __shfl_xor(s, off, 16);
      lrow[qf][r] = s;
    }

  int b_ = bh >> 4, h = bh & 15;
#pragma unroll
  for (int qf = 0; qf < 2; qf++)
#pragma unroll
    for (int r = 0; r < 4; r++) {
      float inv = 1.0f / lrow[qf][r];
      int srow = q0 + qf * 16 + quad * 4 + r;
      size_t base = ((size_t)(b_ * 2048 + srow)) * 5120 + 4096 + h * 64;
#pragma unroll
      for (int n = 0; n < 4; n++)
        cat[base + n * 16 + l15] = f2bf(acc_o[qf][n][r] * inv);
    }
}

// ------------------------------------------------------------------
extern "C" void kernel_launch(void* const* d_in, const int* in_sizes, int n_in,
                              void* d_out, int out_size, void* d_ws, size_t ws_size,
                              hipStream_t stream) {
  (void)in_sizes; (void)n_in; (void)out_size; (void)ws_size;
  const float* x          = (const float*)d_in[0];
  const float* pns        = (const float*)d_in[1];
  const float* w_mlp_in   = (const float*)d_in[2];
  const float* wq         = (const float*)d_in[3];
  const float* wk         = (const float*)d_in[4];
  const float* wv         = (const float*)d_in[5];
  const float* w_mlp_out  = (const float*)d_in[6];
  const float* b_mlp_out  = (const float*)d_in[7];
  const float* w_attn_out = (const float*)d_in[8];
  const float* b_attn_out = (const float*)d_in[9];
  float* out = (float*)d_out;

  char* ws = (char*)d_ws;
  size_t off = 0;
  auto alloc = [&](size_t bytes) {
    void* p = ws + off;
    off += (bytes + 255) & ~(size_t)255;
    return p;
  };
  const size_t M = 8192;
  unsigned short* xn     = (unsigned short*)alloc(M * 1024 * 2);
  unsigned short* wcatT  = (unsigned short*)alloc((size_t)7168 * 1024 * 2);  // [mlp_in|q|k|v][N,K]
  unsigned short* wcat2T = (unsigned short*)alloc((size_t)1024 * 5120 * 2);  // [N=1024, K=5120]
  unsigned short* cat    = (unsigned short*)alloc(M * 5120 * 2);             // [h | av]
  unsigned short* qb     = (unsigned short*)alloc(M * 1024 * 2);
  unsigned short* kb     = (unsigned short*)alloc(M * 1024 * 2);
  unsigned short* vb     = (unsigned short*)alloc(M * 1024 * 2);

  // fused transposes + rmsnorm (independent; both feed gemm6)
  prep_all<<<dim3(20480), 256, 0, stream>>>(
      w_mlp_in, wq, wk, wv, w_mlp_out, w_attn_out, x, pns, wcatT, wcat2T, xn);

  // fused input GEMM: [8192,1024] x [7168,1024]^T; 128x128 tiles,
  // grid 56x64 = 3584 blocks; msplit=2 nsplit=4 (tn=14)
  gemm_bt<6><<<dim3(56, 64), 256, 0, stream>>>(
      xn, wcatT, 1024, cat, nullptr, nullptr, nullptr, 2, 32, 14, qb, kb, vb);

  flash_attn<<<dim3(16, 64), 256, 0, stream>>>(qb, kb, vb, cat);

  // fused output GEMM: [8192,5120] x [1024,5120]^T; 128x128 tiles,
  // grid 8x64 = 512 blocks; msplit=2 nsplit=4 (tn=2)
  gemm_bt<7><<<dim3(8, 64), 256, 0, stream>>>(
      cat, wcat2T, 5120, out, b_mlp_out, b_attn_out, x, 2, 32, 2, nullptr, nullptr, nullptr);
}

// Round 11
// 529.769 us; speedup vs baseline: 1.0166x; 1.0087x over previous
//
#include <hip/hip_runtime.h>
#include <cstdint>
#include <cstddef>

typedef float floatx4 __attribute__((ext_vector_type(4)));
typedef short bf16x8 __attribute__((ext_vector_type(8)));

#define MFMA(a, b, c) __builtin_amdgcn_mfma_f32_16x16x32_bf16((a), (b), (c), 0, 0, 0)

__device__ __forceinline__ unsigned short f2bf(float f) {
  union { float f; unsigned int u; } v; v.f = f;
  unsigned int u = v.u;
  unsigned int r = (u + 0x7FFFu + ((u >> 16) & 1u)) >> 16;
  return (unsigned short)r;
}

__device__ __forceinline__ void gload_lds16(const unsigned short* g, unsigned short* s) {
  __builtin_amdgcn_global_load_lds(
      (const __attribute__((address_space(1))) unsigned int*)g,
      (__attribute__((address_space(3))) unsigned int*)s, 16, 0, 0);
}

// R7-proven gelu (absmax 0.03125).  exp2/rcp variants NOT worth the
// risk: R10's bundled numerics change failed accuracy.
__device__ __forceinline__ float gelu_f(float v) {
  float z = 0.7978845608028654f * (v + 0.044715f * v * v * v);
  float e = __expf(2.0f * z);
  float th = 1.0f - 2.0f / (e + 1.0f);
  return 0.5f * v * (1.0f + th);
}

// ------------------------------------------------------------------
// Fused prep: 6 weight transposes (ids 0..12287) + RMSNorm rows
// (ids 12288..20479).  Transpose: src [R,C] fp32 -> dst [C,R] bf16.
// ------------------------------------------------------------------
__global__ __launch_bounds__(256) void prep_all(
    const float* __restrict__ w_mlp_in, const float* __restrict__ wq,
    const float* __restrict__ wk, const float* __restrict__ wv,
    const float* __restrict__ w_mlp_out, const float* __restrict__ w_attn_out,
    const float* __restrict__ x, const float* __restrict__ pns,
    unsigned short* __restrict__ wcatT, unsigned short* __restrict__ wcat2T,
    unsigned short* __restrict__ xn) {
  __shared__ float tile[32][33];
  __shared__ float ws4[4];
  int id = blockIdx.x;
  if (id >= 12288) {
    // ---- RMSNorm row
    int row = id - 12288;
    const float4 v = ((const float4*)(x + (size_t)row * 1024))[threadIdx.x];
    float ss = v.x * v.x + v.y * v.y + v.z * v.z + v.w * v.w;
#pragma unroll
    for (int off = 1; off < 64; off <<= 1) ss += __shfl_xor(ss, off, 64);
    if ((threadIdx.x & 63) == 0) ws4[threadIdx.x >> 6] = ss;
    __syncthreads();
    float tot = ws4[0] + ws4[1] + ws4[2] + ws4[3];
    float rs = rsqrtf(tot * (1.0f / 1024.0f) + 1e-6f);
    const float4 sc = ((const float4*)pns)[threadIdx.x];
    uint2 o;
    o.x = (unsigned)f2bf(v.x * rs * sc.x) | ((unsigned)f2bf(v.y * rs * sc.y) << 16);
    o.y = (unsigned)f2bf(v.z * rs * sc.z) | ((unsigned)f2bf(v.w * rs * sc.w) << 16);
    ((uint2*)(xn + (size_t)row * 1024))[threadIdx.x] = o;
    return;
  }
  // ---- transpose tile
  const float* src; unsigned short* dst; int C, ldd, bx, by, q;
  if (id < 4096)       { src = w_mlp_in;   dst = wcatT;                        C = 4096; ldd = 1024; q = id;         bx = q & 127; by = q >> 7; }
  else if (id < 5120)  { src = wq;         dst = wcatT + (size_t)4096 * 1024;  C = 1024; ldd = 1024; q = id - 4096;  bx = q & 31;  by = q >> 5; }
  else if (id < 6144)  { src = wk;         dst = wcatT + (size_t)5120 * 1024;  C = 1024; ldd = 1024; q = id - 5120;  bx = q & 31;  by = q >> 5; }
  else if (id < 7168)  { src = wv;         dst = wcatT + (size_t)6144 * 1024;  C = 1024; ldd = 1024; q = id - 6144;  bx = q & 31;  by = q >> 5; }
  else if (id < 11264) { src = w_mlp_out;  dst = wcat2T;                       C = 1024; ldd = 5120; q = id - 7168;  bx = q & 31;  by = q >> 5; }
  else                 { src = w_attn_out; dst = wcat2T + 4096;                C = 1024; ldd = 5120; q = id - 11264; bx = q & 31;  by = q >> 5; }
  int tx = threadIdx.x & 31, ty = threadIdx.x >> 5;
#pragma unroll
  for (int i = 0; i < 4; i++) {
    int r = ty + i * 8;
    tile[r][tx] = src[(size_t)(by * 32 + r) * C + bx * 32 + tx];
  }
  __syncthreads();
#pragma unroll
  for (int i = 0; i < 4; i++) {
    int r = ty + i * 8;
    dst[(size_t)(bx * 32 + r) * ldd + by * 32 + tx] = f2bf(tile[tx][r]);
  }
}

// ------------------------------------------------------------------
// GEMM: C[M,N] = A[M,K] * BT[N,K]^T (both bf16, K-major).  128x128
// tile, BK=64 as 2 x 32-k sub-buffers, 4 waves x 64x64.
// R7 version, measured 160 us MODE6 / MfmaUtil 33.7 / FETCH 127 MB.
//
// nt-stores on all epilogue writes: streaming writes were evicting
// the per-XCD B-panel from L2 (-37us).  f2bf everywhere (cvt_pk
// rounding tripled absmax).  q scale 0.125 EXACT in bf16 (pow2);
// folding log2e into it (R10) broke accuracy -- never prescale by
// non-pow2 before bf16 rounding.
//
// HYBRID SWIZZLE (0 bank conflicts measured): staging lane L ->
// (row L>>2, granule (L&3)^((L>>3)&3)); frag read
// fo=(4*l15+(quad^((l15>>1)&3)))*8.
// ------------------------------------------------------------------
template <int MODE>
__global__ __launch_bounds__(256, 2) void gemm_bt(
    const unsigned short* __restrict__ A, const unsigned short* __restrict__ BT,
    int K, void* __restrict__ outp,
    const float* __restrict__ bias1, const float* __restrict__ bias2,
    const float* __restrict__ resid,
    int msplit, int tm, int tn,
    unsigned short* __restrict__ q_out, unsigned short* __restrict__ k_out,
    unsigned short* __restrict__ v_out) {
  __shared__ unsigned short As[2][128 * 32];
  __shared__ unsigned short Bs[2][128 * 32];

  int id = blockIdx.x + gridDim.x * blockIdx.y;
  int xcd = id & 7, j = id >> 3;
  int mh = xcd % msplit, nq = xcd / msplit;
  int by = mh * tm + j / tn;
  int bx = nq * tn + j % tn;
  int m0 = by * 128, n0 = bx * 128;

  int t = threadIdx.x, lane = t & 63, wave = t >> 6;
  int l15 = lane & 15, quad = lane >> 4;
  int wm = (wave & 1) * 64, wn = (wave >> 1) * 64;

  floatx4 acc[4][4] = {};

  int lr = lane >> 2;
  int lg = (lane & 3) ^ ((lane >> 3) & 3);
  int ch0 = wave * 2, ch1 = wave * 2 + 1;
  const unsigned short* gA0 = A + (size_t)(m0 + ch0 * 16 + lr) * K + lg * 8;
  const unsigned short* gA1 = A + (size_t)(m0 + ch1 * 16 + lr) * K + lg * 8;
  const unsigned short* gB0 = BT + (size_t)(n0 + ch0 * 16 + lr) * K + lg * 8;
  const unsigned short* gB1 = BT + (size_t)(n0 + ch1 * 16 + lr) * K + lg * 8;
  unsigned short* sA0[2] = {&As[0][ch0 * 512 + lane * 8], &As[1][ch0 * 512 + lane * 8]};
  unsigned short* sA1[2] = {&As[0][ch1 * 512 + lane * 8], &As[1][ch1 * 512 + lane * 8]};
  unsigned short* sB0[2] = {&Bs[0][ch0 * 512 + lane * 8], &Bs[1][ch0 * 512 + lane * 8]};
  unsigned short* sB1[2] = {&Bs[0][ch1 * 512 + lane * 8], &Bs[1][ch1 * 512 + lane * 8]};

  int fo = (4 * l15 + (quad ^ ((l15 >> 1) & 3))) * 8;
  int ca = (wm >> 4);
  int cb = (wn >> 4);

  for (int kt = 0; kt < K; kt += 64) {
    __syncthreads();
#pragma unroll
    for (int kk = 0; kk < 2; kk++) {
      int kg = kt + kk * 32;
      gload_lds16(gA0 + kg, sA0[kk]);
      gload_lds16(gA1 + kg, sA1[kk]);
      gload_lds16(gB0 + kg, sB0[kk]);
      gload_lds16(gB1 + kg, sB1[kk]);
    }
    __syncthreads();
#pragma unroll
    for (int kk = 0; kk < 2; kk++) {
      bf16x8 a[4], b[4];
#pragma unroll
      for (int im = 0; im < 4; im++)
        a[im] = *(const bf16x8*)&As[kk][(ca + im) * 512 + fo];
#pragma unroll
      for (int in_ = 0; in_ < 4; in_++)
        b[in_] = *(const bf16x8*)&Bs[kk][(cb + in_) * 512 + fo];
#pragma unroll
      for (int im = 0; im < 4; im++)
#pragma unroll
        for (int in_ = 0; in_ < 4; in_++)
          acc[im][in_] = MFMA(a[im], b[in_], acc[im][in_]);
    }
  }

#pragma unroll
  for (int im = 0; im < 4; im++) {
#pragma unroll
    for (int in_ = 0; in_ < 4; in_++) {
      int row0 = m0 + wm + im * 16 + quad * 4;
      int col = n0 + wn + in_ * 16 + l15;
      if constexpr (MODE == 6) {
        if (n0 < 4096) {
#pragma unroll
          for (int r = 0; r < 4; r++) {
            __builtin_nontemporal_store(f2bf(gelu_f(acc[im][in_][r])),
                &((unsigned short*)outp)[(size_t)(row0 + r) * 5120 + col]);
          }
        } else {
          int seg = (n0 - 4096) >> 10;          // 0=q 1=k 2=v (tile-uniform)
          int cs = col - 4096 - (seg << 10);
          int h = cs >> 6, hd = cs & 63;
          int b_ = row0 >> 11, s0 = row0 & 2047;
          if (seg == 2) {
            // s-consecutive: pack 4 bf16 -> one 64-bit store
            unsigned long long o =
                (unsigned long long)((unsigned)f2bf(acc[im][in_][0]) |
                                     ((unsigned)f2bf(acc[im][in_][1]) << 16)) |
                ((unsigned long long)((unsigned)f2bf(acc[im][in_][2]) |
                                      ((unsigned)f2bf(acc[im][in_][3]) << 16)) << 32);
            __builtin_nontemporal_store(o,
                (unsigned long long*)&v_out[(((size_t)(b_ * 16 + h)) * 64 + hd) * 2048 + s0]);
          } else {
            float sc = (seg == 0) ? 0.125f : 1.0f;
            unsigned short* dst = (seg == 0) ? q_out : k_out;
#pragma unroll
            for (int r = 0; r < 4; r++) {
              __builtin_nontemporal_store(f2bf(acc[im][in_][r] * sc),
                  &dst[(((size_t)(b_ * 16 + h)) * 2048 + s0 + r) * 64 + hd]);
            }
          }
        }
      } else {
        float bsum = bias1[col] + bias2[col];
#pragma unroll
        for (int r = 0; r < 4; r++) {
          size_t idx = (size_t)(row0 + r) * 1024 + col;
          float res = __builtin_nontemporal_load(&resid[idx]);
          __builtin_nontemporal_store(acc[im][in_][r] + bsum + res, &((float*)outp)[idx]);
        }
      }
    }
  }
}

// ------------------------------------------------------------------
// Flash attention, no-max additive variant.  R7 base (q*0.125,
// __expf) with ONE scheduling-only change (bit-identical math):
//
// R11: PV split into c-halves; the exp/f2bf/Ps-write of P cols
// 32..63 sits between the c=0 Ps reads and the c=0 PV MFMAs, so its
// VALU co-issues with the matrix pipe (m114) instead of fully
// serializing.  lrow accumulation order unchanged (cg 0,1 then 2,3).
// Ps wave-private; c1-writes / c0-reads are disjoint; in-order lgkm
// retirement + second lgkmcnt(0) orders the c1 reads.
// ------------------------------------------------------------------
__global__ __launch_bounds__(256, 2) void flash_attn(
    const unsigned short* __restrict__ q_buf, const unsigned short* __restrict__ k_buf,
    const unsigned short* __restrict__ v_buf, unsigned short* __restrict__ cat) {
  constexpr int S = 2048, HD = 64;
  constexpr int LK = 72, LV = 72, LP = 68;
  __shared__ unsigned short Ks[64 * LK];
  __shared__ unsigned short Vs[64 * LV];
  __shared__ unsigned short Ps[4][32 * LP];

  int id = blockIdx.x + gridDim.x * blockIdx.y;   // grid (16, 64)
  int xcd = id & 7, j = id >> 3;                  // j in [0,128)
  int bh = xcd * 8 + (j >> 4);
  int qbk = j & 15;

  int t = threadIdx.x, lane = t & 63, wave = t >> 6;
  int l15 = lane & 15, quad = lane >> 4;

  const unsigned short* qp = q_buf + (size_t)bh * S * HD;
  const unsigned short* kp = k_buf + (size_t)bh * S * HD;
  const unsigned short* vp = v_buf + (size_t)bh * HD * S;

  int q0 = qbk * 128 + wave * 32;
  bf16x8 aQ[2][2];
#pragma unroll
  for (int qf = 0; qf < 2; qf++) {
    aQ[qf][0] = *(const bf16x8*)&qp[(size_t)(q0 + qf * 16 + l15) * HD + quad * 8];
    aQ[qf][1] = *(const bf16x8*)&qp[(size_t)(q0 + qf * 16 + l15) * HD + 32 + quad * 8];
  }

  floatx4 acc_o[2][4] = {};
  float lrow[2][4] = {};

  int kr = t >> 3, kc = (t & 7) * 8;

  uint4 rK0 = *(const uint4*)&kp[(size_t)kr * HD + kc];
  uint4 rK1 = *(const uint4*)&kp[(size_t)(kr + 32) * HD + kc];
  uint4 rV0 = *(const uint4*)&vp[(size_t)kr * S + kc];
  uint4 rV1 = *(const uint4*)&vp[(size_t)(kr + 32) * S + kc];

  for (int kv = 0; kv < S; kv += 64) {
    __syncthreads();
    *(uint4*)&Ks[kr * LK + kc] = rK0;
    *(uint4*)&Ks[(kr + 32) * LK + kc] = rK1;
    *(uint4*)&Vs[kr * LV + kc] = rV0;
    *(uint4*)&Vs[(kr + 32) * LV + kc] = rV1;
    __syncthreads();
    if (kv + 64 < S) {
      rK0 = *(const uint4*)&kp[(size_t)(kv + 64 + kr) * HD + kc];
      rK1 = *(const uint4*)&kp[(size_t)(kv + 64 + kr + 32) * HD + kc];
      rV0 = *(const uint4*)&vp[(size_t)kr * S + kv + 64 + kc];
      rV1 = *(const uint4*)&vp[(size_t)(kr + 32) * S + kv + 64 + kc];
    }

    floatx4 z[2][4];
#pragma unroll
    for (int cg = 0; cg < 4; cg++) {
      bf16x8 bk0 = *(const bf16x8*)&Ks[(cg * 16 + l15) * LK + quad * 8];
      bf16x8 bk1 = *(const bf16x8*)&Ks[(cg * 16 + l15) * LK + 32 + quad * 8];
#pragma unroll
      for (int qf = 0; qf < 2; qf++) {
        floatx4 acc = {};
        acc = MFMA(aQ[qf][0], bk0, acc);
        acc = MFMA(aQ[qf][1], bk1, acc);
        z[qf][cg] = acc;
      }
    }
    // ---- softmax for P cols 0..31 (cg 0,1)
#pragma unroll
    for (int qf = 0; qf < 2; qf++)
#pragma unroll
      for (int cg = 0; cg < 2; cg++)
#pragma unroll
        for (int r = 0; r < 4; r++) {
          float e = __expf(z[qf][cg][r]);
          lrow[qf][r] += e;
          Ps[wave][(qf * 16 + quad * 4 + r) * LP + cg * 16 + l15] = f2bf(e);
        }
    asm volatile("s_waitcnt lgkmcnt(0)" ::: "memory");
    // ---- PV c=0, with cols 32..63 softmax overlapped under MFMAs
    {
      bf16x8 aP[2];
#pragma unroll
      for (int qf = 0; qf < 2; qf++) {
        const unsigned short* pp = &Ps[wave][(qf * 16 + l15) * LP + quad * 8];
        ((uint2*)&aP[qf])[0] = *(const uint2*)pp;
        ((uint2*)&aP[qf])[1] = *(const uint2*)(pp + 4);
      }
#pragma unroll
      for (int qf = 0; qf < 2; qf++)
#pragma unroll
        for (int cg = 2; cg < 4; cg++)
#pragma unroll
          for (int r = 0; r < 4; r++) {
            float e = __expf(z[qf][cg][r]);
            lrow[qf][r] += e;
            Ps[wave][(qf * 16 + quad * 4 + r) * LP + cg * 16 + l15] = f2bf(e);
          }
#pragma unroll
      for (int n = 0; n < 4; n++) {
        bf16x8 bv = *(const bf16x8*)&Vs[(n * 16 + l15) * LV + quad * 8];
        acc_o[0][n] = MFMA(aP[0], bv, acc_o[0][n]);
        acc_o[1][n] = MFMA(aP[1], bv, acc_o[1][n]);
      }
    }
    asm volatile("s_waitcnt lgkmcnt(0)" ::: "memory");
    // ---- PV c=1
    {
      bf16x8 aP[2];
#pragma unroll
      for (int qf = 0; qf < 2; qf++) {
        const unsigned short* pp = &Ps[wave][(qf * 16 + l15) * LP + 32 + quad * 8];
        ((uint2*)&aP[qf])[0] = *(const uint2*)pp;
        ((uint2*)&aP[qf])[1] = *(const uint2*)(pp + 4);
      }
#pragma unroll
      for (int n = 0; n < 4; n++) {
        bf16x8 bv = *(const bf16x8*)&Vs[(n * 16 + l15) * LV + 32 + quad * 8];
        acc_o[0][n] = MFMA(aP[0], bv, acc_o[0][n]);
        acc_o[1][n] = MFMA(aP[1], bv, acc_o[1][n]);
      }
    }
  }

#pragma unroll
  for (int qf = 0; qf < 2; qf++)
#pragma unroll
    for (int r = 0; r < 4; r++) {
      float s = lrow[qf][r];
#pragma unroll
      for (int off = 1; off < 16; off <<= 1) s += __shfl_xor(s, off, 16);
      lrow[qf][r] = s;
    }

  int b_ = bh >> 4, h = bh & 15;
#pragma unroll
  for (int qf = 0; qf < 2; qf++)
#pragma unroll
    for (int r = 0; r < 4; r++) {
      float inv = 1.0f / lrow[qf][r];
      int srow = q0 + qf * 16 + quad * 4 + r;
      size_t base = ((size_t)(b_ * 2048 + srow)) * 5120 + 4096 + h * 64;
#pragma unroll
      for (int n = 0; n < 4; n++)
        cat[base + n * 16 + l15] = f2bf(acc_o[qf][n][r] * inv);
    }
}

// ------------------------------------------------------------------
extern "C" void kernel_launch(void* const* d_in, const int* in_sizes, int n_in,
                              void* d_out, int out_size, void* d_ws, size_t ws_size,
                              hipStream_t stream) {
  (void)in_sizes; (void)n_in; (void)out_size; (void)ws_size;
  const float* x          = (const float*)d_in[0];
  const float* pns        = (const float*)d_in[1];
  const float* w_mlp_in   = (const float*)d_in[2];
  const float* wq         = (const float*)d_in[3];
  const float* wk         = (const float*)d_in[4];
  const float* wv         = (const float*)d_in[5];
  const float* w_mlp_out  = (const float*)d_in[6];
  const float* b_mlp_out  = (const float*)d_in[7];
  const float* w_attn_out = (const float*)d_in[8];
  const float* b_attn_out = (const float*)d_in[9];
  float* out = (float*)d_out;

  char* ws = (char*)d_ws;
  size_t off = 0;
  auto alloc = [&](size_t bytes) {
    void* p = ws + off;
    off += (bytes + 255) & ~(size_t)255;
    return p;
  };
  const size_t M = 8192;
  unsigned short* xn     = (unsigned short*)alloc(M * 1024 * 2);
  unsigned short* wcatT  = (unsigned short*)alloc((size_t)7168 * 1024 * 2);  // [mlp_in|q|k|v][N,K]
  unsigned short* wcat2T = (unsigned short*)alloc((size_t)1024 * 5120 * 2);  // [N=1024, K=5120]
  unsigned short* cat    = (unsigned short*)alloc(M * 5120 * 2);             // [h | av]
  unsigned short* qb     = (unsigned short*)alloc(M * 1024 * 2);
  unsigned short* kb     = (unsigned short*)alloc(M * 1024 * 2);
  unsigned short* vb     = (unsigned short*)alloc(M * 1024 * 2);

  // fused transposes + rmsnorm (independent; both feed gemm6)
  prep_all<<<dim3(20480), 256, 0, stream>>>(
      w_mlp_in, wq, wk, wv, w_mlp_out, w_attn_out, x, pns, wcatT, wcat2T, xn);

  // fused input GEMM: [8192,1024] x [7168,1024]^T; 128x128 tiles,
  // grid 56x64 = 3584 blocks; msplit=2 nsplit=4 (tn=14)
  gemm_bt<6><<<dim3(56, 64), 256, 0, stream>>>(
      xn, wcatT, 1024, cat, nullptr, nullptr, nullptr, 2, 32, 14, qb, kb, vb);

  flash_attn<<<dim3(16, 64), 256, 0, stream>>>(qb, kb, vb, cat);

  // fused output GEMM: [8192,5120] x [1024,5120]^T; 128x128 tiles,
  // grid 8x64 = 512 blocks; msplit=2 nsplit=4 (tn=2)
  gemm_bt<7><<<dim3(8, 64), 256, 0, stream>>>(
      cat, wcat2T, 5120, out, b_mlp_out, b_attn_out, x, 2, 32, 2, nullptr, nullptr, nullptr);
}

// Round 12
// 527.903 us; speedup vs baseline: 1.0202x; 1.0035x over previous
//
#include <hip/hip_runtime.h>
#include <cstdint>
#include <cstddef>

typedef float floatx4 __attribute__((ext_vector_type(4)));
typedef short bf16x8 __attribute__((ext_vector_type(8)));

#define MFMA(a, b, c) __builtin_amdgcn_mfma_f32_16x16x32_bf16((a), (b), (c), 0, 0, 0)

__device__ __forceinline__ unsigned short f2bf(float f) {
  union { float f; unsigned int u; } v; v.f = f;
  unsigned int u = v.u;
  unsigned int r = (u + 0x7FFFu + ((u >> 16) & 1u)) >> 16;
  return (unsigned short)r;
}

__device__ __forceinline__ void gload_lds16(const unsigned short* g, unsigned short* s) {
  __builtin_amdgcn_global_load_lds(
      (const __attribute__((address_space(1))) unsigned int*)g,
      (__attribute__((address_space(3))) unsigned int*)s, 16, 0, 0);
}

// R7-proven gelu (absmax 0.03125).
__device__ __forceinline__ float gelu_f(float v) {
  float z = 0.7978845608028654f * (v + 0.044715f * v * v * v);
  float e = __expf(2.0f * z);
  float th = 1.0f - 2.0f / (e + 1.0f);
  return 0.5f * v * (1.0f + th);
}

// ------------------------------------------------------------------
// Fused prep: 6 weight transposes (ids 0..12287) + RMSNorm rows
// (ids 12288..20479).  Transpose: src [R,C] fp32 -> dst [C,R] bf16.
// ------------------------------------------------------------------
__global__ __launch_bounds__(256) void prep_all(
    const float* __restrict__ w_mlp_in, const float* __restrict__ wq,
    const float* __restrict__ wk, const float* __restrict__ wv,
    const float* __restrict__ w_mlp_out, const float* __restrict__ w_attn_out,
    const float* __restrict__ x, const float* __restrict__ pns,
    unsigned short* __restrict__ wcatT, unsigned short* __restrict__ wcat2T,
    unsigned short* __restrict__ xn) {
  __shared__ float tile[32][33];
  __shared__ float ws4[4];
  int id = blockIdx.x;
  if (id >= 12288) {
    // ---- RMSNorm row
    int row = id - 12288;
    const float4 v = ((const float4*)(x + (size_t)row * 1024))[threadIdx.x];
    float ss = v.x * v.x + v.y * v.y + v.z * v.z + v.w * v.w;
#pragma unroll
    for (int off = 1; off < 64; off <<= 1) ss += __shfl_xor(ss, off, 64);
    if ((threadIdx.x & 63) == 0) ws4[threadIdx.x >> 6] = ss;
    __syncthreads();
    float tot = ws4[0] + ws4[1] + ws4[2] + ws4[3];
    float rs = rsqrtf(tot * (1.0f / 1024.0f) + 1e-6f);
    const float4 sc = ((const float4*)pns)[threadIdx.x];
    uint2 o;
    o.x = (unsigned)f2bf(v.x * rs * sc.x) | ((unsigned)f2bf(v.y * rs * sc.y) << 16);
    o.y = (unsigned)f2bf(v.z * rs * sc.z) | ((unsigned)f2bf(v.w * rs * sc.w) << 16);
    ((uint2*)(xn + (size_t)row * 1024))[threadIdx.x] = o;
    return;
  }
  // ---- transpose tile
  const float* src; unsigned short* dst; int C, ldd, bx, by, q;
  if (id < 4096)       { src = w_mlp_in;   dst = wcatT;                        C = 4096; ldd = 1024; q = id;         bx = q & 127; by = q >> 7; }
  else if (id < 5120)  { src = wq;         dst = wcatT + (size_t)4096 * 1024;  C = 1024; ldd = 1024; q = id - 4096;  bx = q & 31;  by = q >> 5; }
  else if (id < 6144)  { src = wk;         dst = wcatT + (size_t)5120 * 1024;  C = 1024; ldd = 1024; q = id - 5120;  bx = q & 31;  by = q >> 5; }
  else if (id < 7168)  { src = wv;         dst = wcatT + (size_t)6144 * 1024;  C = 1024; ldd = 1024; q = id - 6144;  bx = q & 31;  by = q >> 5; }
  else if (id < 11264) { src = w_mlp_out;  dst = wcat2T;                       C = 1024; ldd = 5120; q = id - 7168;  bx = q & 31;  by = q >> 5; }
  else                 { src = w_attn_out; dst = wcat2T + 4096;                C = 1024; ldd = 5120; q = id - 11264; bx = q & 31;  by = q >> 5; }
  int tx = threadIdx.x & 31, ty = threadIdx.x >> 5;
#pragma unroll
  for (int i = 0; i < 4; i++) {
    int r = ty + i * 8;
    tile[r][tx] = src[(size_t)(by * 32 + r) * C + bx * 32 + tx];
  }
  __syncthreads();
#pragma unroll
  for (int i = 0; i < 4; i++) {
    int r = ty + i * 8;
    dst[(size_t)(bx * 32 + r) * ldd + by * 32 + tx] = f2bf(tile[tx][r]);
  }
}

// ------------------------------------------------------------------
// GEMM core: C[M,N] = A[M,K] * BT[N,K]^T (bf16, row stride lda for
// both A and BT; K = loop bound <= lda).  128x128 tile, BK=64 as
// 2 x 32-k sub-buffers, 4 waves x 64x64.  Verbatim proven structure
// (160us @ MODE6 / MfmaUtil 33 / 0 bank conflicts).
//
// nt-stores on all epilogue writes (proven -37us: streaming writes
// evicted the per-XCD B-panel from L2).  f2bf everywhere.
//
// MODE 6:  fused input epilogue (gelu -> cat | q*0.125/k/v scatter)
// MODE 10: mlp-out partial: out = acc + b1 + b2 + resid  (K=4096)
// MODE 11: attn-out add:    out += acc                   (K=1024)
// ------------------------------------------------------------------
template <int MODE>
__device__ __forceinline__ void gemm_core(
    int xcd, int j,
    const unsigned short* __restrict__ A, const unsigned short* __restrict__ BT,
    int K, int lda, void* __restrict__ outp,
    const float* __restrict__ bias1, const float* __restrict__ bias2,
    const float* __restrict__ resid,
    int msplit, int tm, int tn,
    unsigned short* __restrict__ q_out, unsigned short* __restrict__ k_out,
    unsigned short* __restrict__ v_out,
    unsigned short* As, unsigned short* Bs) {
  int mh = xcd % msplit, nq = xcd / msplit;
  int by = mh * tm + j / tn;
  int bx = nq * tn + j % tn;
  int m0 = by * 128, n0 = bx * 128;

  int t = threadIdx.x, lane = t & 63, wave = t >> 6;
  int l15 = lane & 15, quad = lane >> 4;
  int wm = (wave & 1) * 64, wn = (wave >> 1) * 64;

  floatx4 acc[4][4] = {};

  int lr = lane >> 2;
  int lg = (lane & 3) ^ ((lane >> 3) & 3);
  int ch0 = wave * 2, ch1 = wave * 2 + 1;
  const unsigned short* gA0 = A + (size_t)(m0 + ch0 * 16 + lr) * lda + lg * 8;
  const unsigned short* gA1 = A + (size_t)(m0 + ch1 * 16 + lr) * lda + lg * 8;
  const unsigned short* gB0 = BT + (size_t)(n0 + ch0 * 16 + lr) * lda + lg * 8;
  const unsigned short* gB1 = BT + (size_t)(n0 + ch1 * 16 + lr) * lda + lg * 8;
  unsigned short* sA0[2] = {As + ch0 * 512 + lane * 8, As + 4096 + ch0 * 512 + lane * 8};
  unsigned short* sA1[2] = {As + ch1 * 512 + lane * 8, As + 4096 + ch1 * 512 + lane * 8};
  unsigned short* sB0[2] = {Bs + ch0 * 512 + lane * 8, Bs + 4096 + ch0 * 512 + lane * 8};
  unsigned short* sB1[2] = {Bs + ch1 * 512 + lane * 8, Bs + 4096 + ch1 * 512 + lane * 8};

  int fo = (4 * l15 + (quad ^ ((l15 >> 1) & 3))) * 8;
  int ca = (wm >> 4);
  int cb = (wn >> 4);

  for (int kt = 0; kt < K; kt += 64) {
    __syncthreads();
#pragma unroll
    for (int kk = 0; kk < 2; kk++) {
      int kg = kt + kk * 32;
      gload_lds16(gA0 + kg, sA0[kk]);
      gload_lds16(gA1 + kg, sA1[kk]);
      gload_lds16(gB0 + kg, sB0[kk]);
      gload_lds16(gB1 + kg, sB1[kk]);
    }
    __syncthreads();
#pragma unroll
    for (int kk = 0; kk < 2; kk++) {
      bf16x8 a[4], b[4];
#pragma unroll
      for (int im = 0; im < 4; im++)
        a[im] = *(const bf16x8*)&As[kk * 4096 + (ca + im) * 512 + fo];
#pragma unroll
      for (int in_ = 0; in_ < 4; in_++)
        b[in_] = *(const bf16x8*)&Bs[kk * 4096 + (cb + in_) * 512 + fo];
#pragma unroll
      for (int im = 0; im < 4; im++)
#pragma unroll
        for (int in_ = 0; in_ < 4; in_++)
          acc[im][in_] = MFMA(a[im], b[in_], acc[im][in_]);
    }
  }

#pragma unroll
  for (int im = 0; im < 4; im++) {
#pragma unroll
    for (int in_ = 0; in_ < 4; in_++) {
      int row0 = m0 + wm + im * 16 + quad * 4;
      int col = n0 + wn + in_ * 16 + l15;
      if constexpr (MODE == 6) {
        if (n0 < 4096) {
#pragma unroll
          for (int r = 0; r < 4; r++) {
            __builtin_nontemporal_store(f2bf(gelu_f(acc[im][in_][r])),
                &((unsigned short*)outp)[(size_t)(row0 + r) * 5120 + col]);
          }
        } else {
          int seg = (n0 - 4096) >> 10;          // 0=q 1=k 2=v (tile-uniform)
          int cs = col - 4096 - (seg << 10);
          int h = cs >> 6, hd = cs & 63;
          int b_ = row0 >> 11, s0 = row0 & 2047;
          if (seg == 2) {
            unsigned long long o =
                (unsigned long long)((unsigned)f2bf(acc[im][in_][0]) |
                                     ((unsigned)f2bf(acc[im][in_][1]) << 16)) |
                ((unsigned long long)((unsigned)f2bf(acc[im][in_][2]) |
                                      ((unsigned)f2bf(acc[im][in_][3]) << 16)) << 32);
            __builtin_nontemporal_store(o,
                (unsigned long long*)&v_out[(((size_t)(b_ * 16 + h)) * 64 + hd) * 2048 + s0]);
          } else {
            float sc = (seg == 0) ? 0.125f : 1.0f;   // pow2: exact in bf16
            unsigned short* dst = (seg == 0) ? q_out : k_out;
#pragma unroll
            for (int r = 0; r < 4; r++) {
              __builtin_nontemporal_store(f2bf(acc[im][in_][r] * sc),
                  &dst[(((size_t)(b_ * 16 + h)) * 2048 + s0 + r) * 64 + hd]);
            }
          }
        }
      } else if constexpr (MODE == 10) {
        float bsum = bias1[col] + bias2[col];
#pragma unroll
        for (int r = 0; r < 4; r++) {
          size_t idx = (size_t)(row0 + r) * 1024 + col;
          float res = __builtin_nontemporal_load(&resid[idx]);
          __builtin_nontemporal_store(acc[im][in_][r] + bsum + res, &((float*)outp)[idx]);
        }
      } else {  // MODE 11: out += acc
#pragma unroll
        for (int r = 0; r < 4; r++) {
          size_t idx = (size_t)(row0 + r) * 1024 + col;
          float prev = __builtin_nontemporal_load(&((const float*)outp)[idx]);
          __builtin_nontemporal_store(prev + acc[im][in_][r], &((float*)outp)[idx]);
        }
      }
    }
  }
}

template <int MODE>
__global__ __launch_bounds__(256, 2) void gemm_bt(
    const unsigned short* __restrict__ A, const unsigned short* __restrict__ BT,
    int K, int lda, void* __restrict__ outp,
    const float* __restrict__ bias1, const float* __restrict__ bias2,
    const float* __restrict__ resid,
    int msplit, int tm, int tn,
    unsigned short* __restrict__ q_out, unsigned short* __restrict__ k_out,
    unsigned short* __restrict__ v_out) {
  __shared__ unsigned short As[2 * 128 * 32];
  __shared__ unsigned short Bs[2 * 128 * 32];
  int id = blockIdx.x + gridDim.x * blockIdx.y;
  gemm_core<MODE>(id & 7, id >> 3, A, BT, K, lda, outp, bias1, bias2, resid,
                  msplit, tm, tn, q_out, k_out, v_out, As, Bs);
}

// ------------------------------------------------------------------
// Flash attention body -- R0 VERBATIM (the only proven flash; all 6
// restructure attempts regressed: dbuf +12, LK68 +13, raw-barrier
// +21, LDS-swizzle +14, PV-interleave +9 us).  q pre-scaled 0.125.
// q,k [B,H,S,HD]; v [B,H,HD,S].  av -> cat cols 4096..5120.
// LDS carve: Ks 64*72, Vs 64*72, Ps 4*32*68 shorts (17920 total).
// ------------------------------------------------------------------
__device__ __forceinline__ void flash_body(
    int xcd, int j,
    const unsigned short* __restrict__ q_buf, const unsigned short* __restrict__ k_buf,
    const unsigned short* __restrict__ v_buf, unsigned short* __restrict__ cat,
    unsigned short* smem) {
  constexpr int S = 2048, HD = 64;
  constexpr int LK = 72, LV = 72, LP = 68;
  unsigned short* Ks = smem;
  unsigned short* Vs = smem + 4608;
  unsigned short* Psb = smem + 9216;

  int bh = xcd * 8 + (j >> 4);
  int qbk = j & 15;

  int t = threadIdx.x, lane = t & 63, wave = t >> 6;
  int l15 = lane & 15, quad = lane >> 4;
  unsigned short* Ps = Psb + wave * (32 * LP);

  const unsigned short* qp = q_buf + (size_t)bh * S * HD;
  const unsigned short* kp = k_buf + (size_t)bh * S * HD;
  const unsigned short* vp = v_buf + (size_t)bh * HD * S;

  int q0 = qbk * 128 + wave * 32;
  bf16x8 aQ[2][2];
#pragma unroll
  for (int qf = 0; qf < 2; qf++) {
    aQ[qf][0] = *(const bf16x8*)&qp[(size_t)(q0 + qf * 16 + l15) * HD + quad * 8];
    aQ[qf][1] = *(const bf16x8*)&qp[(size_t)(q0 + qf * 16 + l15) * HD + 32 + quad * 8];
  }

  floatx4 acc_o[2][4] = {};
  float lrow[2][4] = {};

  int kr = t >> 3, kc = (t & 7) * 8;

  uint4 rK0 = *(const uint4*)&kp[(size_t)kr * HD + kc];
  uint4 rK1 = *(const uint4*)&kp[(size_t)(kr + 32) * HD + kc];
  uint4 rV0 = *(const uint4*)&vp[(size_t)kr * S + kc];
  uint4 rV1 = *(const uint4*)&vp[(size_t)(kr + 32) * S + kc];

  for (int kv = 0; kv < S; kv += 64) {
    __syncthreads();
    *(uint4*)&Ks[kr * LK + kc] = rK0;
    *(uint4*)&Ks[(kr + 32) * LK + kc] = rK1;
    *(uint4*)&Vs[kr * LV + kc] = rV0;
    *(uint4*)&Vs[(kr + 32) * LV + kc] = rV1;
    __syncthreads();
    if (kv + 64 < S) {
      rK0 = *(const uint4*)&kp[(size_t)(kv + 64 + kr) * HD + kc];
      rK1 = *(const uint4*)&kp[(size_t)(kv + 64 + kr + 32) * HD + kc];
      rV0 = *(const uint4*)&vp[(size_t)kr * S + kv + 64 + kc];
      rV1 = *(const uint4*)&vp[(size_t)(kr + 32) * S + kv + 64 + kc];
    }

    floatx4 z[2][4];
#pragma unroll
    for (int cg = 0; cg < 4; cg++) {
      bf16x8 bk0 = *(const bf16x8*)&Ks[(cg * 16 + l15) * LK + quad * 8];
      bf16x8 bk1 = *(const bf16x8*)&Ks[(cg * 16 + l15) * LK + 32 + quad * 8];
#pragma unroll
      for (int qf = 0; qf < 2; qf++) {
        floatx4 acc = {};
        acc = MFMA(aQ[qf][0], bk0, acc);
        acc = MFMA(aQ[qf][1], bk1, acc);
        z[qf][cg] = acc;
      }
    }
#pragma unroll
    for (int qf = 0; qf < 2; qf++)
#pragma unroll
      for (int cg = 0; cg < 4; cg++)
#pragma unroll
        for (int r = 0; r < 4; r++) {
          float e = __expf(z[qf][cg][r]);
          lrow[qf][r] += e;
          Ps[(qf * 16 + quad * 4 + r) * LP + cg * 16 + l15] = f2bf(e);
        }
    asm volatile("s_waitcnt lgkmcnt(0)" ::: "memory");
#pragma unroll
    for (int c = 0; c < 2; c++) {
      bf16x8 aP[2];
#pragma unroll
      for (int qf = 0; qf < 2; qf++) {
        const unsigned short* pp = &Ps[(qf * 16 + l15) * LP + c * 32 + quad * 8];
        ((uint2*)&aP[qf])[0] = *(const uint2*)pp;
        ((uint2*)&aP[qf])[1] = *(const uint2*)(pp + 4);
      }
#pragma unroll
      for (int n = 0; n < 4; n++) {
        bf16x8 bv = *(const bf16x8*)&Vs[(n * 16 + l15) * LV + c * 32 + quad * 8];
        acc_o[0][n] = MFMA(aP[0], bv, acc_o[0][n]);
        acc_o[1][n] = MFMA(aP[1], bv, acc_o[1][n]);
      }
    }
  }

#pragma unroll
  for (int qf = 0; qf < 2; qf++)
#pragma unroll
    for (int r = 0; r < 4; r++) {
      float s = lrow[qf][r];
#pragma unroll
      for (int off = 1; off < 16; off <<= 1) s += __shfl_xor(s, off, 16);
      lrow[qf][r] = s;
    }

  int b_ = bh >> 4, h = bh & 15;
#pragma unroll
  for (int qf = 0; qf < 2; qf++)
#pragma unroll
    for (int r = 0; r < 4; r++) {
      float inv = 1.0f / lrow[qf][r];
      int srow = q0 + qf * 16 + quad * 4 + r;
      size_t base = ((size_t)(b_ * 2048 + srow)) * 5120 + 4096 + h * 64;
#pragma unroll
      for (int n = 0; n < 4; n++)
        cat[base + n * 16 + l15] = f2bf(acc_o[qf][n][r] * inv);
    }
}

// ------------------------------------------------------------------
// Fused launch: flash attention (1024 blocks) + MLP-half of the
// output GEMM (512 blocks: [8192, K=4096 of cat] x [1024 rows of
// wcat2T]^T -> out = acc + b1 + b2 + resid).  Independent: gemm7a
// reads cat cols 0..4096 (gemm6 output) and writes out; flash reads
// qb/kb/vb and writes cat cols 4096..5120.  Per-XCD interleave
// (r%3==0 -> gemm) so each CU co-hosts both kinds; the MFMA-heavy
// GEMM fills flash's barrier/latency stalls (m114 overlap; R8
// demonstrated this fusion harness works -- its loss was the input-
// GEMM split, absent here).  LDS union 35840 B.
// ------------------------------------------------------------------
__global__ __launch_bounds__(256, 2) void fused_attn_mlp(
    const unsigned short* __restrict__ qb, const unsigned short* __restrict__ kb,
    const unsigned short* __restrict__ vb, unsigned short* __restrict__ cat,
    const unsigned short* __restrict__ wcat2T, float* __restrict__ out,
    const float* __restrict__ bias1, const float* __restrict__ bias2,
    const float* __restrict__ resid) {
  __shared__ __align__(16) unsigned short smem[17920];
  int phys = blockIdx.x;
  int xcd = phys & 7, r = phys >> 3;        // r in [0,192) per XCD
  if (r % 3 == 0) {
    // gemm7a: j in [0,64) per XCD; msplit=2 tm=32 tn=2 (as old gemm7)
    gemm_core<10>(xcd, r / 3, cat, wcat2T, 4096, 5120, out,
                  bias1, bias2, resid, 2, 32, 2,
                  nullptr, nullptr, nullptr, smem, smem + 8192);
  } else {
    int j = (r / 3) * 2 + (r % 3 - 1);      // [0,128) per XCD
    flash_body(xcd, j, qb, kb, vb, cat, smem);
  }
}

// ------------------------------------------------------------------
extern "C" void kernel_launch(void* const* d_in, const int* in_sizes, int n_in,
                              void* d_out, int out_size, void* d_ws, size_t ws_size,
                              hipStream_t stream) {
  (void)in_sizes; (void)n_in; (void)out_size; (void)ws_size;
  const float* x          = (const float*)d_in[0];
  const float* pns        = (const float*)d_in[1];
  const float* w_mlp_in   = (const float*)d_in[2];
  const float* wq         = (const float*)d_in[3];
  const float* wk         = (const float*)d_in[4];
  const float* wv         = (const float*)d_in[5];
  const float* w_mlp_out  = (const float*)d_in[6];
  const float* b_mlp_out  = (const float*)d_in[7];
  const float* w_attn_out = (const float*)d_in[8];
  const float* b_attn_out = (const float*)d_in[9];
  float* out = (float*)d_out;

  char* ws = (char*)d_ws;
  size_t off = 0;
  auto alloc = [&](size_t bytes) {
    void* p = ws + off;
    off += (bytes + 255) & ~(size_t)255;
    return p;
  };
  const size_t M = 8192;
  unsigned short* xn     = (unsigned short*)alloc(M * 1024 * 2);
  unsigned short* wcatT  = (unsigned short*)alloc((size_t)7168 * 1024 * 2);  // [mlp_in|q|k|v][N,K]
  unsigned short* wcat2T = (unsigned short*)alloc((size_t)1024 * 5120 * 2);  // [N=1024, K=5120]
  unsigned short* cat    = (unsigned short*)alloc(M * 5120 * 2);             // [h | av]
  unsigned short* qb     = (unsigned short*)alloc(M * 1024 * 2);
  unsigned short* kb     = (unsigned short*)alloc(M * 1024 * 2);
  unsigned short* vb     = (unsigned short*)alloc(M * 1024 * 2);

  // fused transposes + rmsnorm (independent; both feed gemm6)
  prep_all<<<dim3(20480), 256, 0, stream>>>(
      w_mlp_in, wq, wk, wv, w_mlp_out, w_attn_out, x, pns, wcatT, wcat2T, xn);

  // fused input GEMM: [8192,1024] x [7168,1024]^T; 128x128 tiles,
  // grid 56x64 = 3584 blocks; msplit=2 nsplit=4 (tn=14)
  gemm_bt<6><<<dim3(56, 64), 256, 0, stream>>>(
      xn, wcatT, 1024, 1024, cat, nullptr, nullptr, nullptr, 2, 32, 14, qb, kb, vb);

  // fused: flash (1024 blocks) + MLP-half output GEMM (512 blocks)
  fused_attn_mlp<<<dim3(1536), 256, 0, stream>>>(
      qb, kb, vb, cat, wcat2T, out, b_mlp_out, b_attn_out, x);

  // attn-half output GEMM: [8192, K=1024 of cat] x wcat2T cols
  // 4096..5120; out += acc.  grid 512; msplit=2 tm=32 tn=2.
  gemm_bt<11><<<dim3(512), 256, 0, stream>>>(
      cat + 4096, wcat2T + 4096, 1024, 5120, out, nullptr, nullptr, nullptr,
      2, 32, 2, nullptr, nullptr, nullptr);
}